// Round 1
// baseline (1153.388 us; speedup 1.0000x reference)
//
#include <hip/hip_runtime.h>
#include <math.h>

#define SEQ   2048
#define DM    1024
#define NHEAD 16
#define HD    64
#define NTOK  4096
#define EPS   1e-5f

// ---------------- LayerNorm: one block per row ----------------
__global__ __launch_bounds__(256) void ln_kernel(
    const float* __restrict__ x, const float* __restrict__ g,
    const float* __restrict__ be, float* __restrict__ y) {
  const int row = blockIdx.x;
  const int t = threadIdx.x;
  const float4 v = ((const float4*)(x + (size_t)row * DM))[t];
  float s  = v.x + v.y + v.z + v.w;
  float ss = v.x*v.x + v.y*v.y + v.z*v.z + v.w*v.w;
  #pragma unroll
  for (int off = 32; off > 0; off >>= 1) {
    s  += __shfl_down(s,  off, 64);
    ss += __shfl_down(ss, off, 64);
  }
  __shared__ float red[8];
  __shared__ float mu_s, rs_s;
  const int wid = t >> 6, lane = t & 63;
  if (lane == 0) { red[wid] = s; red[4 + wid] = ss; }
  __syncthreads();
  if (t == 0) {
    const float S  = red[0] + red[1] + red[2] + red[3];
    const float SS = red[4] + red[5] + red[6] + red[7];
    const float mu  = S * (1.0f / DM);
    const float var = SS * (1.0f / DM) - mu * mu;
    mu_s = mu; rs_s = rsqrtf(var + EPS);
  }
  __syncthreads();
  const float mu = mu_s, r = rs_s;
  const float4 gv = ((const float4*)g)[t];
  const float4 bv = ((const float4*)be)[t];
  float4 o;
  o.x = (v.x - mu) * r * gv.x + bv.x;
  o.y = (v.y - mu) * r * gv.y + bv.y;
  o.z = (v.z - mu) * r * gv.z + bv.z;
  o.w = (v.w - mu) * r * gv.w + bv.w;
  ((float4*)(y + (size_t)row * DM))[t] = o;
}

// ---------------- fp32 GEMM: C[M x 1024] = A[M x 1024] @ W[1024 x 1024] + bias
// 64x64 tile, BK=16, 4x4 per thread. grid = (16, M/64), block = 256.
__global__ __launch_bounds__(256) void gemm_bias(
    const float* __restrict__ A, const float* __restrict__ W,
    const float* __restrict__ bias, float* __restrict__ C) {
  __shared__ float As[16][68];  // [k][m], stride 68: 16B-aligned rows, write conflicts ~2-way
  __shared__ float Bs[16][64];  // [k][n]
  const int tid = threadIdx.x;
  const int tm = tid >> 4, tn = tid & 15;
  const int m0 = blockIdx.y * 64, n0 = blockIdx.x * 64;
  const int lr  = tid >> 2, lc  = tid & 3;   // A staging: row, k-chunk
  const int brk = tid >> 4, bnc = tid & 15;  // B staging: k-row, n-chunk
  float acc[4][4] = {};
  for (int k0 = 0; k0 < DM; k0 += 16) {
    const float4 a = *(const float4*)(A + (size_t)(m0 + lr) * DM + k0 + lc * 4);
    const float4 b = *(const float4*)(W + (size_t)(k0 + brk) * DM + n0 + bnc * 4);
    __syncthreads();
    As[lc*4+0][lr] = a.x; As[lc*4+1][lr] = a.y;
    As[lc*4+2][lr] = a.z; As[lc*4+3][lr] = a.w;
    *(float4*)&Bs[brk][bnc*4] = b;
    __syncthreads();
    #pragma unroll
    for (int kk = 0; kk < 16; ++kk) {
      const float4 av = *(const float4*)&As[kk][tm*4];
      const float4 bv = *(const float4*)&Bs[kk][tn*4];
      acc[0][0] += av.x*bv.x; acc[0][1] += av.x*bv.y; acc[0][2] += av.x*bv.z; acc[0][3] += av.x*bv.w;
      acc[1][0] += av.y*bv.x; acc[1][1] += av.y*bv.y; acc[1][2] += av.y*bv.z; acc[1][3] += av.y*bv.w;
      acc[2][0] += av.z*bv.x; acc[2][1] += av.z*bv.y; acc[2][2] += av.z*bv.z; acc[2][3] += av.z*bv.w;
      acc[3][0] += av.w*bv.x; acc[3][1] += av.w*bv.y; acc[3][2] += av.w*bv.z; acc[3][3] += av.w*bv.w;
    }
  }
  const float4 bb = *(const float4*)(bias + n0 + tn*4);
  #pragma unroll
  for (int a2 = 0; a2 < 4; ++a2) {
    float4 o;
    o.x = acc[a2][0] + bb.x; o.y = acc[a2][1] + bb.y;
    o.z = acc[a2][2] + bb.z; o.w = acc[a2][3] + bb.w;
    *(float4*)(C + (size_t)(m0 + tm*4 + a2) * DM + n0 + tn*4) = o;
  }
}

// ---------------- Flash attention (fp32) ----------------
// grid = (SEQ/64, B*H), block = 256. Each block: 64 queries of one (b,h).
// q,k,v layout: [token][h*64 + d] (token-major, 1024 cols).
__global__ __launch_bounds__(256) void attn_kernel(
    const float* __restrict__ Q, const float* __restrict__ K,
    const float* __restrict__ V, float* __restrict__ O) {
  __shared__ float Qs[64][65];   // [q][d], pre-scaled by 1/8
  __shared__ float KP[64][65];   // K tile [k][d], then reused as P tile [q][k]
  __shared__ float Vs[64][64];   // [k][d]
  const int tid = threadIdx.x;
  const int tm = tid >> 4, tn = tid & 15;
  const int tm4 = tm * 4, tn4 = tn * 4;
  const int q0 = blockIdx.x * 64;
  const int bh = blockIdx.y;
  const size_t base = (size_t)(bh >> 4) * SEQ * DM + (size_t)(bh & 15) * HD;

  #pragma unroll
  for (int i = 0; i < 4; ++i) {
    const int flat = tid + i * 256;
    const int row = flat >> 4, ch = flat & 15;
    const float4 qv = *(const float4*)(Q + base + (size_t)(q0 + row) * DM + ch * 4);
    Qs[row][ch*4+0] = qv.x * 0.125f;
    Qs[row][ch*4+1] = qv.y * 0.125f;
    Qs[row][ch*4+2] = qv.z * 0.125f;
    Qs[row][ch*4+3] = qv.w * 0.125f;
  }

  float o[4][4] = {};
  float mrun[4] = {-1e30f, -1e30f, -1e30f, -1e30f};
  float lrun[4] = {};

  for (int kt = 0; kt < SEQ / 64; ++kt) {
    const int k0 = kt * 64;
    __syncthreads();  // prev PV done (and Q visible on first iter)
    #pragma unroll
    for (int i = 0; i < 4; ++i) {
      const int flat = tid + i * 256;
      const int row = flat >> 4, ch = flat & 15;
      const float4 kv = *(const float4*)(K + base + (size_t)(k0 + row) * DM + ch * 4);
      const float4 vv = *(const float4*)(V + base + (size_t)(k0 + row) * DM + ch * 4);
      KP[row][ch*4+0] = kv.x; KP[row][ch*4+1] = kv.y;
      KP[row][ch*4+2] = kv.z; KP[row][ch*4+3] = kv.w;
      *(float4*)&Vs[row][ch*4] = vv;
    }
    __syncthreads();

    // scores: s[a][b] = sum_d Qs[tm4+a][d] * K[tn4+b][d]
    float s[4][4] = {};
    #pragma unroll 4
    for (int dd = 0; dd < 64; ++dd) {
      const float qa0 = Qs[tm4+0][dd], qa1 = Qs[tm4+1][dd];
      const float qa2 = Qs[tm4+2][dd], qa3 = Qs[tm4+3][dd];
      const float kb0 = KP[tn4+0][dd], kb1 = KP[tn4+1][dd];
      const float kb2 = KP[tn4+2][dd], kb3 = KP[tn4+3][dd];
      s[0][0] += qa0*kb0; s[0][1] += qa0*kb1; s[0][2] += qa0*kb2; s[0][3] += qa0*kb3;
      s[1][0] += qa1*kb0; s[1][1] += qa1*kb1; s[1][2] += qa1*kb2; s[1][3] += qa1*kb3;
      s[2][0] += qa2*kb0; s[2][1] += qa2*kb1; s[2][2] += qa2*kb2; s[2][3] += qa2*kb3;
      s[3][0] += qa3*kb0; s[3][1] += qa3*kb1; s[3][2] += qa3*kb2; s[3][3] += qa3*kb3;
    }

    // online softmax update; rows owned by all threads sharing tm (16-wide shuffles)
    float alpha[4];
    #pragma unroll
    for (int a = 0; a < 4; ++a) {
      float mx = fmaxf(fmaxf(s[a][0], s[a][1]), fmaxf(s[a][2], s[a][3]));
      mx = fmaxf(mx, __shfl_xor(mx, 1, 16));
      mx = fmaxf(mx, __shfl_xor(mx, 2, 16));
      mx = fmaxf(mx, __shfl_xor(mx, 4, 16));
      mx = fmaxf(mx, __shfl_xor(mx, 8, 16));
      const float mnew = fmaxf(mrun[a], mx);
      alpha[a] = __expf(mrun[a] - mnew);
      mrun[a] = mnew;
      s[a][0] = __expf(s[a][0] - mnew); s[a][1] = __expf(s[a][1] - mnew);
      s[a][2] = __expf(s[a][2] - mnew); s[a][3] = __expf(s[a][3] - mnew);
      float ls = s[a][0] + s[a][1] + s[a][2] + s[a][3];
      ls += __shfl_xor(ls, 1, 16);
      ls += __shfl_xor(ls, 2, 16);
      ls += __shfl_xor(ls, 4, 16);
      ls += __shfl_xor(ls, 8, 16);
      lrun[a] = lrun[a] * alpha[a] + ls;
      o[a][0] *= alpha[a]; o[a][1] *= alpha[a];
      o[a][2] *= alpha[a]; o[a][3] *= alpha[a];
    }

    __syncthreads();  // all K reads done before overwriting KP with P
    #pragma unroll
    for (int a = 0; a < 4; ++a) {
      KP[tm4+a][tn4+0] = s[a][0];
      KP[tm4+a][tn4+1] = s[a][1];
      KP[tm4+a][tn4+2] = s[a][2];
      KP[tm4+a][tn4+3] = s[a][3];
    }
    __syncthreads();

    // PV: o[a][c] += sum_j P[tm4+a][j] * Vs[j][tn4+c]
    #pragma unroll 4
    for (int j = 0; j < 64; ++j) {
      const float p0 = KP[tm4+0][j], p1 = KP[tm4+1][j];
      const float p2 = KP[tm4+2][j], p3 = KP[tm4+3][j];
      const float4 vv = *(const float4*)&Vs[j][tn4];
      o[0][0] += p0*vv.x; o[0][1] += p0*vv.y; o[0][2] += p0*vv.z; o[0][3] += p0*vv.w;
      o[1][0] += p1*vv.x; o[1][1] += p1*vv.y; o[1][2] += p1*vv.z; o[1][3] += p1*vv.w;
      o[2][0] += p2*vv.x; o[2][1] += p2*vv.y; o[2][2] += p2*vv.z; o[2][3] += p2*vv.w;
      o[3][0] += p3*vv.x; o[3][1] += p3*vv.y; o[3][2] += p3*vv.z; o[3][3] += p3*vv.w;
    }
  }

  #pragma unroll
  for (int a = 0; a < 4; ++a) {
    const float inv = 1.0f / lrun[a];
    float4 ov;
    ov.x = o[a][0]*inv; ov.y = o[a][1]*inv; ov.z = o[a][2]*inv; ov.w = o[a][3]*inv;
    *(float4*)(O + base + (size_t)(q0 + tm4 + a) * DM + tn4) = ov;
  }
}

extern "C" void kernel_launch(void* const* d_in, const int* in_sizes, int n_in,
                              void* d_out, int out_size, void* d_ws, size_t ws_size,
                              hipStream_t stream) {
  const float* x     = (const float*)d_in[0];
  const float* gamma = (const float*)d_in[1];
  const float* beta  = (const float*)d_in[2];
  const float* wq    = (const float*)d_in[3];
  const float* bq    = (const float*)d_in[4];
  const float* wk    = (const float*)d_in[5];
  const float* bk    = (const float*)d_in[6];
  const float* wv    = (const float*)d_in[7];
  const float* bv    = (const float*)d_in[8];
  const float* wo    = (const float*)d_in[9];
  const float* bo    = (const float*)d_in[10];
  float* out = (float*)d_out;

  float* ws = (float*)d_ws;
  float* xn = ws;                           // 4M floats; reused as attention output
  float* q  = ws + (size_t)4 * 1024 * 1024;
  float* k  = ws + (size_t)8 * 1024 * 1024;
  float* v  = ws + (size_t)12 * 1024 * 1024;
  float* att = xn;  // xn is dead after the QKV GEMMs

  ln_kernel<<<dim3(NTOK), dim3(256), 0, stream>>>(x, gamma, beta, xn);

  dim3 ggrid(DM / 64, NTOK / 64);
  gemm_bias<<<ggrid, dim3(256), 0, stream>>>(xn, wq, bq, q);
  gemm_bias<<<ggrid, dim3(256), 0, stream>>>(xn, wk, bk, k);
  gemm_bias<<<ggrid, dim3(256), 0, stream>>>(xn, wv, bv, v);

  attn_kernel<<<dim3(SEQ / 64, 2 * NHEAD), dim3(256), 0, stream>>>(q, k, v, att);

  gemm_bias<<<ggrid, dim3(256), 0, stream>>>(att, wo, bo, out);
}

// Round 2
// 245.398 us; speedup vs baseline: 4.7001x; 4.7001x over previous
//
#include <hip/hip_runtime.h>
#include <math.h>

#define SEQ   2048
#define DM    1024
#define NHEAD 16
#define HD    64
#define NTOK  4096
#define EPS   1e-5f

typedef __attribute__((ext_vector_type(8))) short v8s;
typedef __attribute__((ext_vector_type(4))) float v4f;
typedef unsigned short ushort_t;

#define GLOAD16(g, l) __builtin_amdgcn_global_load_lds( \
    (const __attribute__((address_space(1))) unsigned int*)(g), \
    (__attribute__((address_space(3))) unsigned int*)(l), 16, 0, 0)

__device__ __forceinline__ unsigned short f2bf(float f) {
  union { float f; unsigned u; } v; v.f = f;
  unsigned r = v.u + 0x7FFFu + ((v.u >> 16) & 1u);
  return (unsigned short)(r >> 16);
}

// ---------------- LayerNorm -> bf16 ----------------
__global__ __launch_bounds__(256) void ln_kernel(
    const float* __restrict__ x, const float* __restrict__ g,
    const float* __restrict__ be, ushort_t* __restrict__ y) {
  const int row = blockIdx.x;
  const int t = threadIdx.x;
  const float4 v = ((const float4*)(x + (size_t)row * DM))[t];
  float s  = v.x + v.y + v.z + v.w;
  float ss = v.x*v.x + v.y*v.y + v.z*v.z + v.w*v.w;
  #pragma unroll
  for (int off = 32; off > 0; off >>= 1) {
    s  += __shfl_down(s,  off, 64);
    ss += __shfl_down(ss, off, 64);
  }
  __shared__ float red[8];
  __shared__ float mu_s, rs_s;
  const int wid = t >> 6, lane = t & 63;
  if (lane == 0) { red[wid] = s; red[4 + wid] = ss; }
  __syncthreads();
  if (t == 0) {
    const float S  = red[0] + red[1] + red[2] + red[3];
    const float SS = red[4] + red[5] + red[6] + red[7];
    const float mu  = S * (1.0f / DM);
    const float var = SS * (1.0f / DM) - mu * mu;
    mu_s = mu; rs_s = rsqrtf(var + EPS);
  }
  __syncthreads();
  const float mu = mu_s, r = rs_s;
  const float4 gv = ((const float4*)g)[t];
  const float4 bv = ((const float4*)be)[t];
  ushort4 o;
  o.x = f2bf((v.x - mu) * r * gv.x + bv.x);
  o.y = f2bf((v.y - mu) * r * gv.y + bv.y);
  o.z = f2bf((v.z - mu) * r * gv.z + bv.z);
  o.w = f2bf((v.w - mu) * r * gv.w + bv.w);
  *(ushort4*)(y + (size_t)row * DM + t * 4) = o;
}

// ---------------- W[k][n] fp32 -> WT[n][k] bf16 ----------------
__global__ __launch_bounds__(256) void wt_kernel(
    const float* __restrict__ w0, const float* __restrict__ w1,
    const float* __restrict__ w2, const float* __restrict__ w3,
    ushort_t* __restrict__ o0, ushort_t* __restrict__ o1,
    ushort_t* __restrict__ o2, ushort_t* __restrict__ o3) {
  const int z = blockIdx.z;
  const float* w = (z==0) ? w0 : (z==1) ? w1 : (z==2) ? w2 : w3;
  ushort_t* o    = (z==0) ? o0 : (z==1) ? o1 : (z==2) ? o2 : o3;
  __shared__ float tile[64][65];
  const int t = threadIdx.x;
  const int n0 = blockIdx.x * 64, k0 = blockIdx.y * 64;
  const int r = t >> 4, c4 = (t & 15) * 4;
  #pragma unroll
  for (int i = 0; i < 4; ++i) {
    const float4 v = *(const float4*)(w + (size_t)(k0 + r + i*16) * DM + n0 + c4);
    tile[r + i*16][c4 + 0] = v.x;
    tile[r + i*16][c4 + 1] = v.y;
    tile[r + i*16][c4 + 2] = v.z;
    tile[r + i*16][c4 + 3] = v.w;
  }
  __syncthreads();
  #pragma unroll
  for (int i = 0; i < 4; ++i) {
    const int n = r + i*16;
    ushort4 o4;
    o4.x = f2bf(tile[c4 + 0][n]);
    o4.y = f2bf(tile[c4 + 1][n]);
    o4.z = f2bf(tile[c4 + 2][n]);
    o4.w = f2bf(tile[c4 + 3][n]);
    *(ushort4*)(o + (size_t)(n0 + n) * DM + k0 + c4) = o4;
  }
}

// ---------------- bf16 MFMA GEMM mainloop (m97 structure) ----------------
// C[128x128] = A[m0.., K] @ WT[n0.., K]^T ; LDS tiles [128 rows][32 k], 64B rows.
__device__ __forceinline__ void gemm_main(ushort_t* lsa, ushort_t* lsb,
    const ushort_t* A, const ushort_t* WT, int m0, int n0, v4f acc[4][4]) {
  const int tid = threadIdx.x;
  const int wid = tid >> 6, lane = tid & 63;
  const int mh = (wid & 1) << 6, nh = (wid >> 1) << 6;
  const int r16 = lane & 15, quad = lane >> 4;
  const int srow = lane >> 2, sch = lane & 3;
  for (int k0 = 0; k0 < DM; k0 += 32) {
    __syncthreads();
    #pragma unroll
    for (int j = 0; j < 2; ++j) {
      const int o = wid * 2 + j;
      GLOAD16(A  + (size_t)(m0 + o*16 + srow) * DM + k0 + sch*8, lsa + o*512);
      GLOAD16(WT + (size_t)(n0 + o*16 + srow) * DM + k0 + sch*8, lsb + o*512);
    }
    __syncthreads();
    v8s af[4], bfr[4];
    #pragma unroll
    for (int i = 0; i < 4; ++i) {
      af[i]  = *(const v8s*)(lsa + (mh + i*16 + r16)*32 + quad*8);
      bfr[i] = *(const v8s*)(lsb + (nh + i*16 + r16)*32 + quad*8);
    }
    #pragma unroll
    for (int i = 0; i < 4; ++i)
      #pragma unroll
      for (int j = 0; j < 4; ++j)
        acc[i][j] = __builtin_amdgcn_mfma_f32_16x16x32_bf16(af[i], bfr[j], acc[i][j], 0, 0, 0);
  }
}

// Fused QKV projections. grid (8, 32, 3). z==2 writes V transposed: Vt[bh][d][t].
__global__ __launch_bounds__(256, 2) void gemm_qkv(const ushort_t* __restrict__ xn,
    const ushort_t* __restrict__ wtq, const ushort_t* __restrict__ wtk, const ushort_t* __restrict__ wtv,
    const float* __restrict__ bq, const float* __restrict__ bk, const float* __restrict__ bv,
    ushort_t* __restrict__ qo, ushort_t* __restrict__ ko, ushort_t* __restrict__ vto) {
  __shared__ ushort_t lsa[128*32];
  __shared__ ushort_t lsb[128*32];
  const int z = blockIdx.z;
  const ushort_t* WT = (z == 0) ? wtq : (z == 1) ? wtk : wtv;
  const float* bias  = (z == 0) ? bq  : (z == 1) ? bk  : bv;
  const int m0 = blockIdx.y * 128, n0 = blockIdx.x * 128;
  v4f acc[4][4];
  #pragma unroll
  for (int i = 0; i < 4; ++i)
    #pragma unroll
    for (int j = 0; j < 4; ++j) acc[i][j] = (v4f){0.f, 0.f, 0.f, 0.f};
  gemm_main(lsa, lsb, xn, WT, m0, n0, acc);
  const int tid = threadIdx.x, wid = tid >> 6, lane = tid & 63;
  const int mh = (wid & 1) << 6, nh = (wid >> 1) << 6;
  const int r16 = lane & 15, quad = lane >> 4;
  if (z < 2) {
    ushort_t* out = (z == 0) ? qo : ko;
    #pragma unroll
    for (int bn = 0; bn < 4; ++bn) {
      const int col = n0 + nh + bn*16 + r16;
      const float bb = bias[col];
      #pragma unroll
      for (int am = 0; am < 4; ++am) {
        const int tb = m0 + mh + am*16 + quad*4;
        #pragma unroll
        for (int r = 0; r < 4; ++r)
          out[(size_t)(tb + r) * DM + col] = f2bf(acc[am][bn][r] + bb);
      }
    }
  } else {
    #pragma unroll
    for (int bn = 0; bn < 4; ++bn) {
      const int col = n0 + nh + bn*16 + r16;
      const float bb = bias[col];
      const int h = col >> 6, d = col & 63;
      #pragma unroll
      for (int am = 0; am < 4; ++am) {
        const int tb = m0 + mh + am*16 + quad*4;
        const int b = tb >> 11, t = tb & 2047;
        ushort4 o4;
        o4.x = f2bf(acc[am][bn][0] + bb);
        o4.y = f2bf(acc[am][bn][1] + bb);
        o4.z = f2bf(acc[am][bn][2] + bb);
        o4.w = f2bf(acc[am][bn][3] + bb);
        *(ushort4*)(vto + ((size_t)(b*NHEAD + h) * HD + d) * SEQ + t) = o4;
      }
    }
  }
}

// Output projection: fp32 out = A @ WTo^T + bo. grid (8, 32).
__global__ __launch_bounds__(256, 2) void gemm_out(const ushort_t* __restrict__ A,
    const ushort_t* __restrict__ WT, const float* __restrict__ bias,
    float* __restrict__ out) {
  __shared__ ushort_t lsa[128*32];
  __shared__ ushort_t lsb[128*32];
  const int m0 = blockIdx.y * 128, n0 = blockIdx.x * 128;
  v4f acc[4][4];
  #pragma unroll
  for (int i = 0; i < 4; ++i)
    #pragma unroll
    for (int j = 0; j < 4; ++j) acc[i][j] = (v4f){0.f, 0.f, 0.f, 0.f};
  gemm_main(lsa, lsb, A, WT, m0, n0, acc);
  const int tid = threadIdx.x, wid = tid >> 6, lane = tid & 63;
  const int mh = (wid & 1) << 6, nh = (wid >> 1) << 6;
  const int r16 = lane & 15, quad = lane >> 4;
  #pragma unroll
  for (int bn = 0; bn < 4; ++bn) {
    const int col = n0 + nh + bn*16 + r16;
    const float bb = bias[col];
    #pragma unroll
    for (int am = 0; am < 4; ++am) {
      const int tb = m0 + mh + am*16 + quad*4;
      #pragma unroll
      for (int r = 0; r < 4; ++r)
        out[(size_t)(tb + r) * DM + col] = acc[am][bn][r] + bb;
    }
  }
}

// ---------------- MFMA flash attention ----------------
// grid (SEQ/64, B*NHEAD), 256 threads = 4 waves; wave owns 16 queries.
// S^T = K·Q^T (softmax in-lane), O^T = V^T·P^T (alpha per-lane scalar).
__global__ __launch_bounds__(256, 2) void attn_kernel(
    const ushort_t* __restrict__ Q, const ushort_t* __restrict__ K,
    const ushort_t* __restrict__ Vt, ushort_t* __restrict__ O) {
  __shared__ ushort_t kbuf[2*64*32];   // [d-half][key][32 d]
  __shared__ ushort_t vbuf[2*64*32];   // [key-half][d][32 keys]
  __shared__ ushort_t ptb[4*2*16*32];  // per-wave [key-half][q][32 keys]
  const int tid = threadIdx.x, wid = tid >> 6, lane = tid & 63;
  const int r16 = lane & 15, quad = lane >> 4;
  const int srow = lane >> 2, sch = lane & 3;
  const int q0 = blockIdx.x * 64, bh = blockIdx.y;
  const int b = bh >> 4, h = bh & 15;
  const ushort_t* gQ = Q + (size_t)b * SEQ * DM + h * HD;
  const ushort_t* gK = K + (size_t)b * SEQ * DM + h * HD;
  const ushort_t* gV = Vt + (size_t)bh * HD * SEQ;
  const int qtok = q0 + wid * 16 + r16;
  const v8s qf0 = *(const v8s*)(gQ + (size_t)qtok * DM + quad * 8);
  const v8s qf1 = *(const v8s*)(gQ + (size_t)qtok * DM + 32 + quad * 8);
  v4f acco[4];
  #pragma unroll
  for (int i = 0; i < 4; ++i) acco[i] = (v4f){0.f, 0.f, 0.f, 0.f};
  float mrun = -1e30f, lrun = 0.f;
  ushort_t* ptw = ptb + wid * 1024;

  for (int kt = 0; kt < SEQ / 64; ++kt) {
    const int k0 = kt * 64;
    __syncthreads();
    #pragma unroll
    for (int j = 0; j < 2; ++j) {
      const int o = wid * 2 + j;
      const int pl = o >> 2, rg = (o & 3) * 16;
      GLOAD16(gK + (size_t)(k0 + rg + srow) * DM + pl*32 + sch*8, kbuf + o*512);
      GLOAD16(gV + (size_t)(rg + srow) * SEQ + k0 + pl*32 + sch*8, vbuf + o*512);
    }
    __syncthreads();

    v4f sacc[4];
    #pragma unroll
    for (int i = 0; i < 4; ++i) sacc[i] = (v4f){0.f, 0.f, 0.f, 0.f};
    #pragma unroll
    for (int g = 0; g < 4; ++g) {
      const v8s ka0 = *(const v8s*)(kbuf + (g*16 + r16)*32 + quad*8);
      const v8s ka1 = *(const v8s*)(kbuf + 2048 + (g*16 + r16)*32 + quad*8);
      sacc[g] = __builtin_amdgcn_mfma_f32_16x16x32_bf16(ka0, qf0, sacc[g], 0, 0, 0);
      sacc[g] = __builtin_amdgcn_mfma_f32_16x16x32_bf16(ka1, qf1, sacc[g], 0, 0, 0);
    }

    float sv[16];
    float mloc = -1e30f;
    #pragma unroll
    for (int i = 0; i < 16; ++i) {
      sv[i] = sacc[i >> 2][i & 3] * 0.125f;
      mloc = fmaxf(mloc, sv[i]);
    }
    mloc = fmaxf(mloc, __shfl_xor(mloc, 16, 64));
    mloc = fmaxf(mloc, __shfl_xor(mloc, 32, 64));
    const float mnew = fmaxf(mrun, mloc);
    const float alpha = __expf(mrun - mnew);
    float ls = 0.f;
    #pragma unroll
    for (int i = 0; i < 16; ++i) { sv[i] = __expf(sv[i] - mnew); ls += sv[i]; }
    ls += __shfl_xor(ls, 16, 64);
    ls += __shfl_xor(ls, 32, 64);
    mrun = mnew;
    lrun = lrun * alpha + ls;

    #pragma unroll
    for (int g = 0; g < 4; ++g)
      #pragma unroll
      for (int r = 0; r < 4; ++r) {
        const int key = g*16 + quad*4 + r;
        ptw[(key >> 5)*512 + r16*32 + (key & 31)] = f2bf(sv[g*4 + r]);
      }
    #pragma unroll
    for (int dg = 0; dg < 4; ++dg) acco[dg] *= alpha;

    const v8s pb0 = *(const v8s*)(ptw + r16*32 + quad*8);
    const v8s pb1 = *(const v8s*)(ptw + 512 + r16*32 + quad*8);
    #pragma unroll
    for (int dg = 0; dg < 4; ++dg) {
      const v8s va0 = *(const v8s*)(vbuf + (dg*16 + r16)*32 + quad*8);
      const v8s va1 = *(const v8s*)(vbuf + 2048 + (dg*16 + r16)*32 + quad*8);
      acco[dg] = __builtin_amdgcn_mfma_f32_16x16x32_bf16(va0, pb0, acco[dg], 0, 0, 0);
      acco[dg] = __builtin_amdgcn_mfma_f32_16x16x32_bf16(va1, pb1, acco[dg], 0, 0, 0);
    }
  }

  const float inv = 1.f / lrun;
  ushort_t* gO = O + (size_t)b * SEQ * DM + h * HD;
  #pragma unroll
  for (int dg = 0; dg < 4; ++dg) {
    ushort4 o4;
    o4.x = f2bf(acco[dg][0] * inv);
    o4.y = f2bf(acco[dg][1] * inv);
    o4.z = f2bf(acco[dg][2] * inv);
    o4.w = f2bf(acco[dg][3] * inv);
    *(ushort4*)(gO + (size_t)qtok * DM + dg*16 + quad*4) = o4;
  }
}

extern "C" void kernel_launch(void* const* d_in, const int* in_sizes, int n_in,
                              void* d_out, int out_size, void* d_ws, size_t ws_size,
                              hipStream_t stream) {
  const float* x     = (const float*)d_in[0];
  const float* gamma = (const float*)d_in[1];
  const float* beta  = (const float*)d_in[2];
  const float* wq    = (const float*)d_in[3];
  const float* bq    = (const float*)d_in[4];
  const float* wk    = (const float*)d_in[5];
  const float* bk    = (const float*)d_in[6];
  const float* wv    = (const float*)d_in[7];
  const float* bv    = (const float*)d_in[8];
  const float* wo    = (const float*)d_in[9];
  const float* bo    = (const float*)d_in[10];
  float* out = (float*)d_out;

  unsigned char* w8 = (unsigned char*)d_ws;
  const size_t MB = 1024 * 1024;
  ushort_t* xn  = (ushort_t*)(w8 + 0 * MB);   // 8 MB; reused as attention output
  ushort_t* qb  = (ushort_t*)(w8 + 8 * MB);
  ushort_t* kb  = (ushort_t*)(w8 + 16 * MB);
  ushort_t* vt  = (ushort_t*)(w8 + 24 * MB);
  ushort_t* wtq = (ushort_t*)(w8 + 32 * MB);
  ushort_t* wtk = (ushort_t*)(w8 + 34 * MB);
  ushort_t* wtv = (ushort_t*)(w8 + 36 * MB);
  ushort_t* wto = (ushort_t*)(w8 + 38 * MB);
  ushort_t* ob  = xn;

  ln_kernel<<<dim3(NTOK), dim3(256), 0, stream>>>(x, gamma, beta, xn);
  wt_kernel<<<dim3(16, 16, 4), dim3(256), 0, stream>>>(wq, wk, wv, wo, wtq, wtk, wtv, wto);
  gemm_qkv<<<dim3(8, 32, 3), dim3(256), 0, stream>>>(xn, wtq, wtk, wtv, bq, bk, bv, qb, kb, vt);
  attn_kernel<<<dim3(SEQ / 64, 2 * NHEAD), dim3(256), 0, stream>>>(qb, kb, vt, ob);
  gemm_out<<<dim3(8, 32, 1), dim3(256), 0, stream>>>(ob, wto, bo, out);
}